// Round 1
// baseline (105.974 us; speedup 1.0000x reference)
//
#include <hip/hip_runtime.h>
#include <math.h>

#define BSZ 4096
#define DIM 256
// 20 * log2(e): rows are pre-scaled by sqrt(20*log2e)/||row|| so the MFMA
// emits u = score*log2e; exp2(u - SC20L2E) == exp(score - 20) exactly.
#define SC20L2E 28.853900817779268f

#if __has_builtin(__builtin_amdgcn_exp2f)
#define EXP2F(x) __builtin_amdgcn_exp2f(x)
#else
#define EXP2F(x) exp2f(x)
#endif

typedef int   intx4    __attribute__((ext_vector_type(4)));
typedef int   intx8    __attribute__((ext_vector_type(8)));
typedef float floatx16 __attribute__((ext_vector_type(16)));

__device__ __forceinline__ void async_cp16(void* lds, const void* g) {
    __builtin_amdgcn_global_load_lds(
        (__attribute__((address_space(1))) unsigned int*)(unsigned long long)g,
        (__attribute__((address_space(3))) unsigned int*)lds,
        16, 0, 0);
}

// One wave per row index: load row r of all 4 matrices once.
// Outputs: fp8 e4m3 rows pre-scaled by sqrt(20*log2e)/||row||, fp32 diagonal
// scores for the 4 pairs; zeroes rowsum/colsum; inits out[0]=40 (const term).
__global__ __launch_bounds__(256)
void prep_kernel(const float* __restrict__ a0, const float* __restrict__ a1,
                 const float* __restrict__ a2, const float* __restrict__ a3,
                 unsigned char* __restrict__ f8, float* __restrict__ diag,
                 float* __restrict__ rowsum, float* __restrict__ colsum,
                 float* __restrict__ out) {
    const float* srcs[4] = {a0, a1, a2, a3};
    int w = threadIdx.x >> 6, lane = threadIdx.x & 63;
    int row = blockIdx.x * 4 + w;

    float4 v[4];
    float red[8];
    #pragma unroll
    for (int m = 0; m < 4; m++) {
        v[m] = ((const float4*)(srcs[m] + (size_t)row * DIM))[lane];
        red[m] = v[m].x * v[m].x + v[m].y * v[m].y + v[m].z * v[m].z + v[m].w * v[m].w;
    }
    // pair dots: (0,1) (0,2) (1,2) (1,3)
    red[4] = v[0].x * v[1].x + v[0].y * v[1].y + v[0].z * v[1].z + v[0].w * v[1].w;
    red[5] = v[0].x * v[2].x + v[0].y * v[2].y + v[0].z * v[2].z + v[0].w * v[2].w;
    red[6] = v[1].x * v[2].x + v[1].y * v[2].y + v[1].z * v[2].z + v[1].w * v[2].w;
    red[7] = v[1].x * v[3].x + v[1].y * v[3].y + v[1].z * v[3].z + v[1].w * v[3].w;

    #pragma unroll
    for (int i = 0; i < 8; i++) {
        #pragma unroll
        for (int s = 32; s; s >>= 1) red[i] += __shfl_xor(red[i], s, 64);
    }

    float rinv[4];
    #pragma unroll
    for (int m = 0; m < 4; m++) rinv[m] = rsqrtf(fmaxf(red[m], 1e-24f));

    const float sq = sqrtf(SC20L2E);
    #pragma unroll
    for (int m = 0; m < 4; m++) {
        float sc = sq * rinv[m];
        int pk = __builtin_amdgcn_cvt_pk_fp8_f32(v[m].x * sc, v[m].y * sc, 0, false);
        pk = __builtin_amdgcn_cvt_pk_fp8_f32(v[m].z * sc, v[m].w * sc, pk, true);
        ((unsigned int*)(f8 + (size_t)m * BSZ * DIM))[row * 64 + lane] = (unsigned int)pk;
    }

    if (lane == 0) {
        diag[0 * BSZ + row] = red[4] * 20.0f * rinv[0] * rinv[1];
        diag[1 * BSZ + row] = red[5] * 20.0f * rinv[0] * rinv[2];
        diag[2 * BSZ + row] = red[6] * 20.0f * rinv[1] * rinv[2];
        diag[3 * BSZ + row] = red[7] * 20.0f * rinv[1] * rinv[3];
    }
    if (blockIdx.x < 64) {
        int idx = blockIdx.x * 256 + threadIdx.x;
        rowsum[idx] = 0.f;
        colsum[idx] = 0.f;
        if (idx == 0) out[0] = 40.0f;   // + 20*4B/(2B) constant term
    }
}

// 128x128 tile of exp(score-20) per block (pair = blockIdx.z).
// MX-scaled fp8 MFMA (mfma_scale_f32_32x32x64_f8f6f4, unit E8M0 scales).
//
// K pipelined as 4 phases of K=64 with DOUBLE-BUFFERED LDS in 32 KB
// (2 bufs x (8KB A + 8KB B)) -> still 4 blocks/CU at (256,4).
// T3+T4: counted s_waitcnt vmcnt(4) + raw s_barrier keeps phase p+1's
// staging in flight across compute(p); only the last phase drains to 0.
// T5: s_setprio(1) around each MFMA cluster (phase-split schedule regime).
//
// LDS layout per 64B row: 4 chunks of 16B, slot(row,c) = (c ^ (row>>1)) & 3
// (involution; 8 consecutive rows hit 8 distinct bank-quads -> 4-way max
// conflict, same as the previous 128B-row swizzle). Fragment read addr =
// [row*64 + (((row>>1)&3)<<4)] ^ (h<<5) ^ (j<<4), bases hoisted per lane.
// A/B operand layout (32x32x64): row = lane&31, k = (lane>>5)*32 + byte.
// C/D layout (32x32): col = lane&31, row = (reg&3)+8*(reg>>2)+4*(lane>>5).
// Accumulators init to -SC20L2E so the epilogue is a bare v_exp_f32.
__global__ __launch_bounds__(256, 4)
void pair_scores_kernel(const unsigned char* __restrict__ f8,
                        float* __restrict__ rowsum,
                        float* __restrict__ colsum) {
    const int PX[4] = {0, 0, 1, 1};
    const int PY[4] = {1, 2, 2, 3};
    int p = blockIdx.z;
    const unsigned char* Xb = f8 + (size_t)PX[p] * BSZ * DIM;
    const unsigned char* Yb = f8 + (size_t)PY[p] * BSZ * DIM;
    float* rs = rowsum + p * BSZ;
    float* cs = colsum + p * BSZ;

    __shared__ __align__(16) unsigned char smem[32768];  // 2 bufs x 16 KB

    int tid  = threadIdx.x;
    int lane = tid & 63;
    int w    = tid >> 6;
    int wm = w >> 1, wn = w & 1;
    int l5 = lane & 31, h = lane >> 5;
    int bi = blockIdx.x * 128, bj = blockIdx.y * 128;

    // Hoisted fragment read bases (within a 16 KB buffer):
    // addr(row, c=h*2+j) = row*64 + (((c ^ (row>>1))&3)<<4)
    //                    = [row*64 + (((row>>1)&3)<<4)] ^ (h<<5) ^ (j<<4)
    unsigned qa[2], qb[2];
    #pragma unroll
    for (int t = 0; t < 2; t++) {
        int ra = wm * 64 + t * 32 + l5;
        int rb = wn * 64 + t * 32 + l5;
        qa[t] = (unsigned)(ra * 64 + (((ra >> 1) & 3) << 4)) ^ (unsigned)(h << 5);
        qb[t] = (unsigned)(8192 + rb * 64 + (((rb >> 1) & 3) << 4)) ^ (unsigned)(h << 5);
    }

    // Staging: 512 slots of 16B per panel per phase; slot s = i*256 + tid,
    // row = s>>2, q = s&3, chunk c = (q ^ (row>>1))&3 (same involution as
    // the read side). LDS dest is wave-uniform base + lane*16 (cp16 rule);
    // the swizzle is applied on the per-lane GLOBAL source address.
    const unsigned char* gA[2];
    const unsigned char* gB[2];
    unsigned sbase[2];
    #pragma unroll
    for (int i = 0; i < 2; i++) {
        int s   = i * 256 + tid;
        int row = s >> 2;
        int c   = (s ^ (row >> 1)) & 3;
        sbase[i] = (unsigned)((i * 256 + w * 64) * 16);   // wave-uniform
        gA[i] = Xb + (size_t)(bi + row) * 256 + c * 16;
        gB[i] = Yb + (size_t)(bj + row) * 256 + c * 16;
    }

#define STAGE(PH, BUF) do {                                                  \
        _Pragma("unroll")                                                    \
        for (int i = 0; i < 2; i++) {                                        \
            async_cp16(smem + (BUF) * 16384 + sbase[i],        gA[i] + (PH) * 64); \
            async_cp16(smem + (BUF) * 16384 + 8192 + sbase[i], gB[i] + (PH) * 64); \
        }                                                                    \
    } while (0)

#define WAITVM(N) asm volatile("s_waitcnt vmcnt(" #N ")" ::: "memory")
#define BAR() __builtin_amdgcn_s_barrier()

#define COMPUTE(BUF) do {                                                    \
        intx8 A[2], B[2];                                                    \
        _Pragma("unroll")                                                    \
        for (int t = 0; t < 2; t++) {                                        \
            unsigned a0 = (BUF) * 16384u + qa[t];                            \
            intx4 lo = *(const intx4*)(smem + a0);                           \
            intx4 hi = *(const intx4*)(smem + (a0 ^ 16u));                   \
            A[t] = (intx8){lo[0], lo[1], lo[2], lo[3], hi[0], hi[1], hi[2], hi[3]}; \
            unsigned b0 = (BUF) * 16384u + qb[t];                            \
            intx4 bl = *(const intx4*)(smem + b0);                           \
            intx4 bh = *(const intx4*)(smem + (b0 ^ 16u));                   \
            B[t] = (intx8){bl[0], bl[1], bl[2], bl[3], bh[0], bh[1], bh[2], bh[3]}; \
        }                                                                    \
        __builtin_amdgcn_s_setprio(1);                                       \
        _Pragma("unroll")                                                    \
        for (int i = 0; i < 2; i++)                                          \
            _Pragma("unroll")                                                \
            for (int j = 0; j < 2; j++)                                      \
                acc[i][j] = __builtin_amdgcn_mfma_scale_f32_32x32x64_f8f6f4( \
                    A[i], B[j], acc[i][j], 0, 0,                             \
                    0, 0x7F7F7F7F, 0, 0x7F7F7F7F);                           \
        __builtin_amdgcn_s_setprio(0);                                       \
    } while (0)

    // Prologue: two phases in flight (8 cp16/thread outstanding).
    STAGE(0, 0);
    STAGE(1, 1);

    floatx16 acc[2][2];
    #pragma unroll
    for (int i = 0; i < 2; i++)
        #pragma unroll
        for (int j = 0; j < 2; j++)
            #pragma unroll
            for (int r = 0; r < 16; r++)
                acc[i][j][r] = -SC20L2E;

    // p=0: wait stage0 (stage1 stays in flight), compute buf0, then refill.
    WAITVM(4); BAR();
    COMPUTE(0);
    BAR();                    // all waves done reading buf0
    STAGE(2, 0);
    // p=1
    WAITVM(4); BAR();
    COMPUTE(1);
    BAR();                    // all waves done reading buf1
    STAGE(3, 1);
    // p=2
    WAITVM(4); BAR();
    COMPUTE(0);
    // p=3 (no refill after p=2; only the final drain remains)
    WAITVM(0); BAR();
    COMPUTE(1);

#undef STAGE
#undef WAITVM
#undef BAR
#undef COMPUTE

    // ---- epilogue: exp2 (raw v_exp_f32), butterfly reductions, atomics ----
    #pragma unroll
    for (int i = 0; i < 2; i++)
        #pragma unroll
        for (int j = 0; j < 2; j++)
            #pragma unroll
            for (int r = 0; r < 16; r++)
                acc[i][j][r] = EXP2F(acc[i][j][r]);

    // Row sums: v[t], t = ti*16 + reg, reduced over the 32 l5-lanes via
    // 5-level value-splitting butterfly; lane l5 ends holding v[l5].
    float v[32];
    #pragma unroll
    for (int t = 0; t < 2; t++)
        #pragma unroll
        for (int r = 0; r < 16; r++)
            v[t * 16 + r] = acc[t][0][r] + acc[t][1][r];

    float u1[16];
    #pragma unroll
    for (int k = 0; k < 16; k++) {
        float snd = (l5 & 1) ? v[2 * k] : v[2 * k + 1];
        float got = __shfl_xor(snd, 1, 64);
        u1[k] = ((l5 & 1) ? v[2 * k + 1] : v[2 * k]) + got;
    }
    float u2[8];
    #pragma unroll
    for (int k = 0; k < 8; k++) {
        float snd = ((l5 >> 1) & 1) ? u1[2 * k] : u1[2 * k + 1];
        float got = __shfl_xor(snd, 2, 64);
        u2[k] = (((l5 >> 1) & 1) ? u1[2 * k + 1] : u1[2 * k]) + got;
    }
    float u3[4];
    #pragma unroll
    for (int k = 0; k < 4; k++) {
        float snd = ((l5 >> 2) & 1) ? u2[2 * k] : u2[2 * k + 1];
        float got = __shfl_xor(snd, 4, 64);
        u3[k] = (((l5 >> 2) & 1) ? u2[2 * k + 1] : u2[2 * k]) + got;
    }
    float u4[2];
    #pragma unroll
    for (int k = 0; k < 2; k++) {
        float snd = ((l5 >> 3) & 1) ? u3[2 * k] : u3[2 * k + 1];
        float got = __shfl_xor(snd, 8, 64);
        u4[k] = (((l5 >> 3) & 1) ? u3[2 * k + 1] : u3[2 * k]) + got;
    }
    {
        float snd = ((l5 >> 4) & 1) ? u4[0] : u4[1];
        float got = __shfl_xor(snd, 16, 64);
        float wr = (((l5 >> 4) & 1) ? u4[1] : u4[0]) + got;
        // lane l5 holds row-sum for t=l5: ti = l5>>4, reg = l5&15
        int reg = l5 & 15;
        int row = bi + wm * 64 + (l5 >> 4) * 32
                + (reg & 3) + 8 * (reg >> 2) + 4 * h;
        atomicAdd(&rs[row], wr);
    }

    // Col sums: c[tj] = sum over both ti tiles' 16 regs; reduce over the two
    // h-halves (xor 32); lane ends holding the col-sum for tj = h.
    float c0 = 0.f, c1 = 0.f;
    #pragma unroll
    for (int t = 0; t < 2; t++)
        #pragma unroll
        for (int r = 0; r < 16; r++) {
            c0 += acc[t][0][r];
            c1 += acc[t][1][r];
        }
    {
        float snd = h ? c0 : c1;
        float got = __shfl_xor(snd, 32, 64);
        float cc = (h ? c1 : c0) + got;
        atomicAdd(&cs[bj + wn * 64 + h * 32 + l5], cc);
    }
}

// 64 blocks: each thread one (pair,row) entry; wave-reduce then atomicAdd
// into out (prep pre-set out = 40, the 20*4B/(2B) constant).
__global__ __launch_bounds__(256)
void final_reduce_kernel(const float* __restrict__ rowsum,
                         const float* __restrict__ colsum,
                         const float* __restrict__ diag,
                         float* __restrict__ out) {
    int idx = blockIdx.x * 256 + threadIdx.x;
    float acc = 0.5f * (__logf(rowsum[idx]) + __logf(colsum[idx])) - diag[idx];
    #pragma unroll
    for (int s = 32; s; s >>= 1) acc += __shfl_xor(acc, s, 64);
    if ((threadIdx.x & 63) == 0)
        atomicAdd(out, acc * (1.0f / (2.0f * BSZ)));
}

extern "C" void kernel_launch(void* const* d_in, const int* in_sizes, int n_in,
                              void* d_out, int out_size, void* d_ws, size_t ws_size,
                              hipStream_t stream) {
    const float* in_anchor = (const float*)d_in[0];
    const float* in_pos    = (const float*)d_in[1];
    // d_in[2] (reference_anchor) intentionally unused, matching the reference.
    const float* in_rtext  = (const float*)d_in[3];
    const float* in_rvis   = (const float*)d_in[4];

    char* ws = (char*)d_ws;
    unsigned char* f8 = (unsigned char*)ws;                 // 4 * B * D fp8
    size_t f8_bytes = (size_t)4 * BSZ * DIM;
    float* rowsum = (float*)(ws + f8_bytes);                // 4 * B
    float* colsum = rowsum + 4 * BSZ;                       // 4 * B
    float* diag   = colsum + 4 * BSZ;                       // 4 * B

    prep_kernel<<<BSZ / 4, 256, 0, stream>>>(
        in_anchor, in_pos, in_rtext, in_rvis, f8, diag, rowsum, colsum,
        (float*)d_out);

    pair_scores_kernel<<<dim3(BSZ / 128, BSZ / 128, 4), 256, 0, stream>>>(
        f8, rowsum, colsum);

    final_reduce_kernel<<<64, 256, 0, stream>>>(
        rowsum, colsum, diag, (float*)d_out);
}

// Round 2
// 105.606 us; speedup vs baseline: 1.0035x; 1.0035x over previous
//
#include <hip/hip_runtime.h>
#include <math.h>

#define BSZ 4096
#define DIM 256
// 20 * log2(e): rows are pre-scaled by sqrt(20*log2e)/||row|| so the MFMA
// emits u = score*log2e; exp2(u - SC20L2E) == exp(score - 20) exactly.
#define SC20L2E 28.853900817779268f

#if __has_builtin(__builtin_amdgcn_exp2f)
#define EXP2F(x) __builtin_amdgcn_exp2f(x)
#else
#define EXP2F(x) exp2f(x)
#endif

typedef int   intx4    __attribute__((ext_vector_type(4)));
typedef int   intx8    __attribute__((ext_vector_type(8)));
typedef float floatx16 __attribute__((ext_vector_type(16)));

// f8 layout: per matrix m (1 MB), 8 K-panels of [BSZ rows][32 bytes]:
//   byte (row, k)  ->  m*BSZ*DIM + (k>>5)*(BSZ*32) + row*32 + (k&31)
// This makes every 32x32x64 MFMA fragment (row = lane&31, k = h*32 + b)
// a contiguous 32-byte per-lane load; 32 consecutive lanes read 1 KB of
// contiguous memory -> perfectly coalesced, no LDS staging needed at all.

// One wave per row index: load row r of all 4 matrices once.
// Outputs: fp8 e4m3 rows pre-scaled by sqrt(20*log2e)/||row|| in K-panel
// layout, fp32 diagonal scores for the 4 pairs; zeroes rowsum/colsum;
// inits out[0]=40 (const term).
__global__ __launch_bounds__(256)
void prep_kernel(const float* __restrict__ a0, const float* __restrict__ a1,
                 const float* __restrict__ a2, const float* __restrict__ a3,
                 unsigned char* __restrict__ f8, float* __restrict__ diag,
                 float* __restrict__ rowsum, float* __restrict__ colsum,
                 float* __restrict__ out) {
    const float* srcs[4] = {a0, a1, a2, a3};
    int w = threadIdx.x >> 6, lane = threadIdx.x & 63;
    int row = blockIdx.x * 4 + w;

    float4 v[4];
    float red[8];
    #pragma unroll
    for (int m = 0; m < 4; m++) {
        v[m] = ((const float4*)(srcs[m] + (size_t)row * DIM))[lane];
        red[m] = v[m].x * v[m].x + v[m].y * v[m].y + v[m].z * v[m].z + v[m].w * v[m].w;
    }
    // pair dots: (0,1) (0,2) (1,2) (1,3)
    red[4] = v[0].x * v[1].x + v[0].y * v[1].y + v[0].z * v[1].z + v[0].w * v[1].w;
    red[5] = v[0].x * v[2].x + v[0].y * v[2].y + v[0].z * v[2].z + v[0].w * v[2].w;
    red[6] = v[1].x * v[2].x + v[1].y * v[2].y + v[1].z * v[2].z + v[1].w * v[2].w;
    red[7] = v[1].x * v[3].x + v[1].y * v[3].y + v[1].z * v[3].z + v[1].w * v[3].w;

    #pragma unroll
    for (int i = 0; i < 8; i++) {
        #pragma unroll
        for (int s = 32; s; s >>= 1) red[i] += __shfl_xor(red[i], s, 64);
    }

    float rinv[4];
    #pragma unroll
    for (int m = 0; m < 4; m++) rinv[m] = rsqrtf(fmaxf(red[m], 1e-24f));

    const float sq = sqrtf(SC20L2E);
    #pragma unroll
    for (int m = 0; m < 4; m++) {
        float sc = sq * rinv[m];
        int pk = __builtin_amdgcn_cvt_pk_fp8_f32(v[m].x * sc, v[m].y * sc, 0, false);
        pk = __builtin_amdgcn_cvt_pk_fp8_f32(v[m].z * sc, v[m].w * sc, pk, true);
        // lane holds fp8 bytes k = 4*lane .. 4*lane+3:
        //   panel = lane>>3, int index within panel = row*8 + (lane&7)
        ((unsigned int*)(f8 + (size_t)m * BSZ * DIM
                            + (size_t)(lane >> 3) * (BSZ * 32)))
            [row * 8 + (lane & 7)] = (unsigned int)pk;
    }

    if (lane == 0) {
        diag[0 * BSZ + row] = red[4] * 20.0f * rinv[0] * rinv[1];
        diag[1 * BSZ + row] = red[5] * 20.0f * rinv[0] * rinv[2];
        diag[2 * BSZ + row] = red[6] * 20.0f * rinv[1] * rinv[2];
        diag[3 * BSZ + row] = red[7] * 20.0f * rinv[1] * rinv[3];
    }
    if (blockIdx.x < 64) {
        int idx = blockIdx.x * 256 + threadIdx.x;
        rowsum[idx] = 0.f;
        colsum[idx] = 0.f;
        if (idx == 0) out[0] = 40.0f;   // + 20*4B/(2B) constant term
    }
}

// 128x128 tile of exp(score-20) per block (pair = blockIdx.z).
// MX-scaled fp8 MFMA (mfma_scale_f32_32x32x64_f8f6f4, unit E8M0 scales).
//
// NO LDS, NO barriers: with K=256 and f8 fully L2-resident (4 MB), LDS
// staging was pure overhead (768 MB of LDS ops + cp16 constraints + 8
// barriers/block). The K-panel f8 layout makes each fragment a contiguous
// per-lane 32B global load (2x dwordx4), coalesced across the 32 l5-lanes.
// Per-block working set is 16 KB -> L1-resident; wm/wn waves share A/B
// panels through L1. 4 straight-line K-steps of {8 loads + 4 MFMA},
// independently schedulable across 16 waves/CU -> latency fully hidden.
//
// A/B operand layout (32x32x64): row = lane&31, k = (lane>>5)*32 + byte.
// C/D layout (32x32): col = lane&31, row = (reg&3)+8*(reg>>2)+4*(lane>>5).
// Accumulators init to -SC20L2E so the epilogue is a bare v_exp_f32.
__global__ __launch_bounds__(256, 4)
void pair_scores_kernel(const unsigned char* __restrict__ f8,
                        float* __restrict__ rowsum,
                        float* __restrict__ colsum) {
    const int PX[4] = {0, 0, 1, 1};
    const int PY[4] = {1, 2, 2, 3};
    int p = blockIdx.z;
    const unsigned char* Xb = f8 + (size_t)PX[p] * BSZ * DIM;
    const unsigned char* Yb = f8 + (size_t)PY[p] * BSZ * DIM;
    float* rs = rowsum + p * BSZ;
    float* cs = colsum + p * BSZ;

    int tid  = threadIdx.x;
    int lane = tid & 63;
    int w    = tid >> 6;
    int wm = w >> 1, wn = w & 1;
    int l5 = lane & 31, h = lane >> 5;
    int bi = blockIdx.x * 128, bj = blockIdx.y * 128;

    // Per-lane fragment base pointers (panel h folded in; ks adds
    // 2 panels = BSZ*64 bytes per K-step).
    const unsigned char* pa[2];
    const unsigned char* pb[2];
    #pragma unroll
    for (int t = 0; t < 2; t++) {
        int ra = bi + wm * 64 + t * 32 + l5;
        int rb = bj + wn * 64 + t * 32 + l5;
        pa[t] = Xb + (size_t)h * (BSZ * 32) + (size_t)ra * 32;
        pb[t] = Yb + (size_t)h * (BSZ * 32) + (size_t)rb * 32;
    }

    floatx16 acc[2][2];
    #pragma unroll
    for (int i = 0; i < 2; i++)
        #pragma unroll
        for (int j = 0; j < 2; j++)
            #pragma unroll
            for (int r = 0; r < 16; r++)
                acc[i][j][r] = -SC20L2E;

    #pragma unroll
    for (int ks = 0; ks < 4; ks++) {
        const size_t ko = (size_t)ks * (BSZ * 64);   // 2 panels per K-step
        intx8 A[2], B[2];
        #pragma unroll
        for (int t = 0; t < 2; t++) {
            intx4 lo = *(const intx4*)(pa[t] + ko);
            intx4 hi = *(const intx4*)(pa[t] + ko + 16);
            A[t] = (intx8){lo[0], lo[1], lo[2], lo[3], hi[0], hi[1], hi[2], hi[3]};
            intx4 bl = *(const intx4*)(pb[t] + ko);
            intx4 bh = *(const intx4*)(pb[t] + ko + 16);
            B[t] = (intx8){bl[0], bl[1], bl[2], bl[3], bh[0], bh[1], bh[2], bh[3]};
        }
        #pragma unroll
        for (int i = 0; i < 2; i++)
            #pragma unroll
            for (int j = 0; j < 2; j++)
                acc[i][j] = __builtin_amdgcn_mfma_scale_f32_32x32x64_f8f6f4(
                    A[i], B[j], acc[i][j], 0, 0,
                    0, 0x7F7F7F7F, 0, 0x7F7F7F7F);
    }

    // ---- epilogue: exp2 (raw v_exp_f32), butterfly reductions, atomics ----
    #pragma unroll
    for (int i = 0; i < 2; i++)
        #pragma unroll
        for (int j = 0; j < 2; j++)
            #pragma unroll
            for (int r = 0; r < 16; r++)
                acc[i][j][r] = EXP2F(acc[i][j][r]);

    // Row sums: v[t], t = ti*16 + reg, reduced over the 32 l5-lanes via
    // 5-level value-splitting butterfly; lane l5 ends holding v[l5].
    float v[32];
    #pragma unroll
    for (int t = 0; t < 2; t++)
        #pragma unroll
        for (int r = 0; r < 16; r++)
            v[t * 16 + r] = acc[t][0][r] + acc[t][1][r];

    float u1[16];
    #pragma unroll
    for (int k = 0; k < 16; k++) {
        float snd = (l5 & 1) ? v[2 * k] : v[2 * k + 1];
        float got = __shfl_xor(snd, 1, 64);
        u1[k] = ((l5 & 1) ? v[2 * k + 1] : v[2 * k]) + got;
    }
    float u2[8];
    #pragma unroll
    for (int k = 0; k < 8; k++) {
        float snd = ((l5 >> 1) & 1) ? u1[2 * k] : u1[2 * k + 1];
        float got = __shfl_xor(snd, 2, 64);
        u2[k] = (((l5 >> 1) & 1) ? u1[2 * k + 1] : u1[2 * k]) + got;
    }
    float u3[4];
    #pragma unroll
    for (int k = 0; k < 4; k++) {
        float snd = ((l5 >> 2) & 1) ? u2[2 * k] : u2[2 * k + 1];
        float got = __shfl_xor(snd, 4, 64);
        u3[k] = (((l5 >> 2) & 1) ? u2[2 * k + 1] : u2[2 * k]) + got;
    }
    float u4[2];
    #pragma unroll
    for (int k = 0; k < 2; k++) {
        float snd = ((l5 >> 3) & 1) ? u3[2 * k] : u3[2 * k + 1];
        float got = __shfl_xor(snd, 8, 64);
        u4[k] = (((l5 >> 3) & 1) ? u3[2 * k + 1] : u3[2 * k]) + got;
    }
    {
        float snd = ((l5 >> 4) & 1) ? u4[0] : u4[1];
        float got = __shfl_xor(snd, 16, 64);
        float wr = (((l5 >> 4) & 1) ? u4[1] : u4[0]) + got;
        // lane l5 holds row-sum for t=l5: ti = l5>>4, reg = l5&15
        int reg = l5 & 15;
        int row = bi + wm * 64 + (l5 >> 4) * 32
                + (reg & 3) + 8 * (reg >> 2) + 4 * h;
        atomicAdd(&rs[row], wr);
    }

    // Col sums: c[tj] = sum over both ti tiles' 16 regs; reduce over the two
    // h-halves (xor 32); lane ends holding the col-sum for tj = h.
    float c0 = 0.f, c1 = 0.f;
    #pragma unroll
    for (int t = 0; t < 2; t++)
        #pragma unroll
        for (int r = 0; r < 16; r++) {
            c0 += acc[t][0][r];
            c1 += acc[t][1][r];
        }
    {
        float snd = h ? c0 : c1;
        float got = __shfl_xor(snd, 32, 64);
        float cc = (h ? c1 : c0) + got;
        atomicAdd(&cs[bj + wn * 64 + h * 32 + l5], cc);
    }
}

// 64 blocks: each thread one (pair,row) entry; wave-reduce then atomicAdd
// into out (prep pre-set out = 40, the 20*4B/(2B) constant).
__global__ __launch_bounds__(256)
void final_reduce_kernel(const float* __restrict__ rowsum,
                         const float* __restrict__ colsum,
                         const float* __restrict__ diag,
                         float* __restrict__ out) {
    int idx = blockIdx.x * 256 + threadIdx.x;
    float acc = 0.5f * (__logf(rowsum[idx]) + __logf(colsum[idx])) - diag[idx];
    #pragma unroll
    for (int s = 32; s; s >>= 1) acc += __shfl_xor(acc, s, 64);
    if ((threadIdx.x & 63) == 0)
        atomicAdd(out, acc * (1.0f / (2.0f * BSZ)));
}

extern "C" void kernel_launch(void* const* d_in, const int* in_sizes, int n_in,
                              void* d_out, int out_size, void* d_ws, size_t ws_size,
                              hipStream_t stream) {
    const float* in_anchor = (const float*)d_in[0];
    const float* in_pos    = (const float*)d_in[1];
    // d_in[2] (reference_anchor) intentionally unused, matching the reference.
    const float* in_rtext  = (const float*)d_in[3];
    const float* in_rvis   = (const float*)d_in[4];

    char* ws = (char*)d_ws;
    unsigned char* f8 = (unsigned char*)ws;                 // 4 * B * D fp8 (K-panel layout)
    size_t f8_bytes = (size_t)4 * BSZ * DIM;
    float* rowsum = (float*)(ws + f8_bytes);                // 4 * B
    float* colsum = rowsum + 4 * BSZ;                       // 4 * B
    float* diag   = colsum + 4 * BSZ;                       // 4 * B

    prep_kernel<<<BSZ / 4, 256, 0, stream>>>(
        in_anchor, in_pos, in_rtext, in_rvis, f8, diag, rowsum, colsum,
        (float*)d_out);

    pair_scores_kernel<<<dim3(BSZ / 128, BSZ / 128, 4), 256, 0, stream>>>(
        f8, rowsum, colsum);

    final_reduce_kernel<<<64, 256, 0, stream>>>(
        rowsum, colsum, diag, (float*)d_out);
}